// Round 1
// baseline (3376.937 us; speedup 1.0000x reference)
//
#include <hip/hip_runtime.h>
#include <stdint.h>

typedef __attribute__((ext_vector_type(8))) short s16x8;
typedef __attribute__((ext_vector_type(8))) unsigned short u16x8;
typedef __attribute__((ext_vector_type(4))) float f32x4;

__device__ inline unsigned short f2b(float f){
  unsigned u = __builtin_bit_cast(unsigned, f);
  u = u + 0x7fffu + ((u >> 16) & 1u);
  return (unsigned short)(u >> 16);
}
__device__ inline float b2f(unsigned short h){
  unsigned u = ((unsigned)h) << 16;
  return __builtin_bit_cast(float, u);
}

typedef __attribute__((address_space(1))) const unsigned g_uint;
typedef __attribute__((address_space(3))) unsigned l_uint;

__device__ inline void gload_lds16(const void* g, void* l){
  __builtin_amdgcn_global_load_lds((g_uint*)reinterpret_cast<uintptr_t>(g),
                                   (l_uint*)reinterpret_cast<uintptr_t>(l), 16, 0, 0);
}

// C[m][n] = sum_k A[m][k] * B[n][k]   (A: [M,K], B: [N,K], both row-major bf16)
// EPI 0: Cf[idx] = v*scale          (fp32 out)
// EPI 1: Cb[idx] = bf16(v*scale)
// EPI 2: Cb[idx] = bf16(v + bias[row])
// EPI 3: o = Cf[idx] + v; Cf[idx] = o; Cb[idx] = bf16(o)
template<int EPI>
__global__ __launch_bounds__(256, 2) void gemm_bt(
    const unsigned short* __restrict__ A, const unsigned short* __restrict__ B,
    int M, int N, int K, float scale, const float* __restrict__ bias,
    float* __restrict__ Cf, unsigned short* __restrict__ Cb)
{
  __shared__ unsigned short As[128*64];
  __shared__ unsigned short Bs[128*64];
  const int tid  = threadIdx.x;
  const int wid  = tid >> 6, lane = tid & 63;
  const int wr   = wid >> 1, wc = wid & 1;
  const int bm   = blockIdx.y * 128, bn = blockIdx.x * 128;

  f32x4 acc[4][4] = {};

  // ---- staging geometry (global source pre-swizzled; LDS written linearly) ----
  // linear LDS byte = chunk*1024 + lane*16 ; row = chunk*8 + (lane>>3)
  // element (row,col) lives at byte row*128 + ((col*2) ^ ((row&7)<<4))
  const int l8   = lane >> 3;                         // row within 8-row chunk
  const int scol = ((((lane & 7) << 4) ^ (l8 << 4)) >> 1); // source col (elements)

  const unsigned short* Ag[4]; const unsigned short* Bg[4];
  unsigned short* Al[4]; unsigned short* Bl[4];
  #pragma unroll
  for (int i = 0; i < 4; ++i){
    const int row = wid*32 + i*8 + l8;
    Ag[i] = A + (size_t)(bm + row) * K + scol;
    Bg[i] = B + (size_t)(bn + row) * K + scol;
    Al[i] = As + (wid*4 + i) * 512;
    Bl[i] = Bs + (wid*4 + i) * 512;
  }

  // ---- fragment read geometry ----
  const int fr    = lane & 15;
  const int fk    = (lane >> 4) << 4;      // byte offset of k-group within 32-elem slab
  const int amask = (fr & 7) << 4;         // swizzle mask (row&7)<<4

  for (int k0 = 0; k0 < K; k0 += 64){
    if (k0) __syncthreads();
    #pragma unroll
    for (int i = 0; i < 4; ++i){
      gload_lds16(Ag[i] + k0, Al[i]);
      gload_lds16(Bg[i] + k0, Bl[i]);
    }
    __syncthreads();
    #pragma unroll
    for (int kk = 0; kk < 2; ++kk){
      s16x8 af[4], bf[4];
      #pragma unroll
      for (int m = 0; m < 4; ++m){
        const int row = (wr << 6) + m*16 + fr;
        const int off = row*128 + (((kk << 6) + fk) ^ amask);
        af[m] = *(const s16x8*)((const char*)As + off);
      }
      #pragma unroll
      for (int n = 0; n < 4; ++n){
        const int row = (wc << 6) + n*16 + fr;
        const int off = row*128 + (((kk << 6) + fk) ^ amask);
        bf[n] = *(const s16x8*)((const char*)Bs + off);
      }
      #pragma unroll
      for (int m = 0; m < 4; ++m)
        #pragma unroll
        for (int n = 0; n < 4; ++n)
          acc[m][n] = __builtin_amdgcn_mfma_f32_16x16x32_bf16(af[m], bf[n], acc[m][n], 0, 0, 0);
    }
  }

  // ---- epilogue ----
  const int gr0 = bm + (wr << 6) + ((lane >> 4) << 2);
  const int gc0 = bn + (wc << 6) + (lane & 15);
  #pragma unroll
  for (int m = 0; m < 4; ++m){
    #pragma unroll
    for (int n = 0; n < 4; ++n){
      #pragma unroll
      for (int j = 0; j < 4; ++j){
        const int row = gr0 + m*16 + j;
        const int col = gc0 + n*16;
        const size_t idx = (size_t)row * N + col;
        const float v = acc[m][n][j];
        if      (EPI == 0) Cf[idx] = v * scale;
        else if (EPI == 1) Cb[idx] = f2b(v * scale);
        else if (EPI == 2) Cb[idx] = f2b(v + bias[row]);
        else { const float o = Cf[idx] + v; Cf[idx] = o; Cb[idx] = f2b(o); }
      }
    }
  }
}

// fp32 -> (optional fp32 copy) + bf16, 8 elements/thread
__global__ void cvt8(const float* __restrict__ src, float* __restrict__ dstf,
                     unsigned short* __restrict__ dstb, int n8)
{
  const int i = blockIdx.x * 256 + threadIdx.x;
  if (i >= n8) return;
  const f32x4 a = ((const f32x4*)src)[2*i];
  const f32x4 b = ((const f32x4*)src)[2*i + 1];
  if (dstf){ ((f32x4*)dstf)[2*i] = a; ((f32x4*)dstf)[2*i + 1] = b; }
  u16x8 o;
  o[0]=f2b(a[0]); o[1]=f2b(a[1]); o[2]=f2b(a[2]); o[3]=f2b(a[3]);
  o[4]=f2b(b[0]); o[5]=f2b(b[1]); o[6]=f2b(b[2]); o[7]=f2b(b[3]);
  ((u16x8*)dstb)[i] = o;
}

// softmax over 4096 fp32 cols, one block (256 thr) per row -> bf16 att
__global__ __launch_bounds__(256) void softmax_f32(const float* __restrict__ z,
                                                   unsigned short* __restrict__ att)
{
  const int row = blockIdx.x, t = threadIdx.x;
  const int lane = t & 63, wid = t >> 6;
  __shared__ float red[4];
  const f32x4* zr = (const f32x4*)(z + (size_t)row * 4096) + t*4;
  f32x4 v[4];
  #pragma unroll
  for (int i = 0; i < 4; ++i) v[i] = zr[i];
  float m = -3.0e38f;
  #pragma unroll
  for (int i = 0; i < 4; ++i)
    #pragma unroll
    for (int j = 0; j < 4; ++j) m = fmaxf(m, v[i][j]);
  #pragma unroll
  for (int o = 32; o; o >>= 1) m = fmaxf(m, __shfl_xor(m, o, 64));
  if (lane == 0) red[wid] = m;
  __syncthreads();
  m = fmaxf(fmaxf(red[0], red[1]), fmaxf(red[2], red[3]));
  float e[16]; float s = 0.f;
  #pragma unroll
  for (int i = 0; i < 4; ++i)
    #pragma unroll
    for (int j = 0; j < 4; ++j){ const float x = __expf(v[i][j] - m); e[i*4+j] = x; s += x; }
  #pragma unroll
  for (int o = 32; o; o >>= 1) s += __shfl_xor(s, o, 64);
  __syncthreads();
  if (lane == 0) red[wid] = s;
  __syncthreads();
  s = red[0] + red[1] + red[2] + red[3];
  const float inv = 1.0f / s;
  u16x8 o0, o1;
  #pragma unroll
  for (int j = 0; j < 8; ++j){ o0[j] = f2b(e[j] * inv); o1[j] = f2b(e[8+j] * inv); }
  u16x8* out = (u16x8*)(att + (size_t)row * 4096 + t*16);
  out[0] = o0; out[1] = o1;
}

// in-place softmax over 16384 bf16 cols, one block (1024 thr) per row
__global__ __launch_bounds__(1024) void softmax_b16(unsigned short* __restrict__ z2)
{
  const int row = blockIdx.x, t = threadIdx.x;
  const int lane = t & 63, wid = t >> 6;
  __shared__ float red[16];
  u16x8* p = (u16x8*)(z2 + (size_t)row * 16384 + t*16);
  const u16x8 a0 = p[0], a1 = p[1];
  float x[16];
  #pragma unroll
  for (int j = 0; j < 8; ++j){ x[j] = b2f(a0[j]); x[8+j] = b2f(a1[j]); }
  float m = -3.0e38f;
  #pragma unroll
  for (int j = 0; j < 16; ++j) m = fmaxf(m, x[j]);
  #pragma unroll
  for (int o = 32; o; o >>= 1) m = fmaxf(m, __shfl_xor(m, o, 64));
  if (lane == 0) red[wid] = m;
  __syncthreads();
  #pragma unroll
  for (int i = 0; i < 16; ++i) m = fmaxf(m, red[i]);
  float e[16]; float s = 0.f;
  #pragma unroll
  for (int j = 0; j < 16; ++j){ const float xx = __expf(x[j] - m); e[j] = xx; s += xx; }
  #pragma unroll
  for (int o = 32; o; o >>= 1) s += __shfl_xor(s, o, 64);
  __syncthreads();
  if (lane == 0) red[wid] = s;
  __syncthreads();
  s = 0.f;
  #pragma unroll
  for (int i = 0; i < 16; ++i) s += red[i];
  const float inv = 1.0f / s;
  u16x8 o0, o1;
  #pragma unroll
  for (int j = 0; j < 8; ++j){ o0[j] = f2b(e[j] * inv); o1[j] = f2b(e[8+j] * inv); }
  p[0] = o0; p[1] = o1;
}

extern "C" void kernel_launch(void* const* d_in, const int* in_sizes, int n_in,
                              void* d_out, int out_size, void* d_ws, size_t ws_size,
                              hipStream_t stream)
{
  (void)in_sizes; (void)n_in; (void)out_size; (void)ws_size;
  const float* sents = (const float*)d_in[0];
  const float* funcs = (const float*)d_in[1];
  const float* WvA   = (const float*)d_in[2];   // Wv_f2s
  const float* bvA   = (const float*)d_in[3];
  const float* WvB   = (const float*)d_in[4];   // Wv_s2f
  const float* bvB   = (const float*)d_in[5];

  const int NS = 16384, NF = 4096, D = 768;

  float* outS = (float*)d_out;                        // [NS, D]
  float* outF = outS + (size_t)NS * D;                // [NF, D]
  float* outZ = outF + (size_t)NF * D;                // [NS, NF]

  char* ws = (char*)d_ws;
  unsigned short* att = (unsigned short*)ws;  ws += (size_t)NS * NF * 2;   // shared att / z2 buffer
  unsigned short* z2  = att;                                               // disjoint lifetimes
  unsigned short* sb  = (unsigned short*)ws;  ws += (size_t)NS * D * 2;
  unsigned short* fb  = (unsigned short*)ws;  ws += (size_t)NF * D * 2;
  unsigned short* fvT = (unsigned short*)ws;  ws += (size_t)D * NF * 2;
  unsigned short* svT = (unsigned short*)ws;  ws += (size_t)D * NS * 2;
  unsigned short* wA  = (unsigned short*)ws;  ws += (size_t)D * D * 2;
  unsigned short* wB  = (unsigned short*)ws;  ws += (size_t)D * D * 2;

  const float scale = 0.036084391824351615f;  // 1/sqrt(768)

  cvt8<<<dim3((NS*D/8 + 255)/256), 256, 0, stream>>>(sents, outS, sb, NS*D/8);
  cvt8<<<dim3((NF*D/8 + 255)/256), 256, 0, stream>>>(funcs, outF, fb, NF*D/8);
  cvt8<<<dim3((D*D/8 + 255)/256),  256, 0, stream>>>(WvA, nullptr, wA, D*D/8);
  cvt8<<<dim3((D*D/8 + 255)/256),  256, 0, stream>>>(WvB, nullptr, wB, D*D/8);

  for (int it = 0; it < 4; ++it){
    // fvT[d][f] = sum_k Wv_f2s[d][k]*func_hid[f][k] + bv_f2s[d]   (= func_val^T)
    gemm_bt<2><<<dim3(NF/128, D/128), dim3(256), 0, stream>>>(wA, fb, D, NF, D, 0.f, bvA, nullptr, fvT);
    // z = scale * sents_hid @ func_hid^T   (fp32, in d_out)
    gemm_bt<0><<<dim3(NF/128, NS/128), dim3(256), 0, stream>>>(sb, fb, NS, NF, D, scale, nullptr, outZ, nullptr);
    softmax_f32<<<NS, 256, 0, stream>>>(outZ, att);
    // sents_hid += att @ func_val ; refresh bf16 copy
    gemm_bt<3><<<dim3(D/128, NS/128), dim3(256), 0, stream>>>(att, fvT, NS, D, NF, 0.f, nullptr, outS, sb);
    // svT[d][s] = sum_k Wv_s2f[d][k]*sents_hid[s][k] + bv_s2f[d]  (= sent_val^T)
    gemm_bt<2><<<dim3(NS/128, D/128), dim3(256), 0, stream>>>(wB, sb, D, NS, D, 0.f, bvB, nullptr, svT);
    // z2 = scale * func_hid @ sents_hid^T   (bf16)
    gemm_bt<1><<<dim3(NS/128, NF/128), dim3(256), 0, stream>>>(fb, sb, NF, NS, D, scale, nullptr, nullptr, z2);
    softmax_b16<<<NF, 1024, 0, stream>>>(z2);
    // func_hid += att2 @ sent_val ; refresh bf16 copy
    gemm_bt<3><<<dim3(D/128, NF/128), dim3(256), 0, stream>>>(z2, svT, NF, D, NS, 0.f, nullptr, outF, fb);
  }
}

// Round 2
// 3176.612 us; speedup vs baseline: 1.0631x; 1.0631x over previous
//
#include <hip/hip_runtime.h>
#include <stdint.h>

typedef __attribute__((ext_vector_type(8))) short s16x8;
typedef __attribute__((ext_vector_type(8))) unsigned short u16x8;
typedef __attribute__((ext_vector_type(4))) unsigned short u16x4;
typedef __attribute__((ext_vector_type(4))) float f32x4;

__device__ inline unsigned short f2b(float f){
  unsigned u = __builtin_bit_cast(unsigned, f);
  u = u + 0x7fffu + ((u >> 16) & 1u);
  return (unsigned short)(u >> 16);
}
__device__ inline float b2f(unsigned short h){
  unsigned u = ((unsigned)h) << 16;
  return __builtin_bit_cast(float, u);
}

typedef __attribute__((address_space(1))) const unsigned g_uint;
typedef __attribute__((address_space(3))) unsigned l_uint;

__device__ inline void gload_lds16(const void* g, void* l){
  __builtin_amdgcn_global_load_lds((g_uint*)reinterpret_cast<uintptr_t>(g),
                                   (l_uint*)reinterpret_cast<uintptr_t>(l), 16, 0, 0);
}

// C[m][n] = sum_k A[m][k] * B[n][k]   (A: [M,K], B: [N,K], both row-major bf16)
// K range per block: [blockIdx.z*KS, blockIdx.z*KS+KS)
// EPI 0: Cf[idx] = v*scale                       (fp32 out)
// EPI 1: Cb[idx] = bf16(v*scale)
// EPI 2: Cb[idx] = bf16(v + bias[row])
// EPI 4: Cf[blockIdx.z*M*N + idx] = v            (split-K partial)
template<int EPI>
__global__ __launch_bounds__(256, 2) void gemm_bt(
    const unsigned short* __restrict__ A, const unsigned short* __restrict__ B,
    int M, int N, int KS, float scale, const float* __restrict__ bias,
    float* __restrict__ Cf, unsigned short* __restrict__ Cb)
{
  __shared__ unsigned short As[128*64];
  __shared__ unsigned short Bs[128*64];
  const int tid  = threadIdx.x;
  const int wid  = tid >> 6, lane = tid & 63;
  const int wr   = wid >> 1, wc = wid & 1;
  const int bm   = blockIdx.y * 128, bn = blockIdx.x * 128;
  const int kb   = blockIdx.z * KS, ke = kb + KS;

  f32x4 acc[4][4] = {};

  // ---- staging geometry (global source pre-swizzled; LDS written linearly) ----
  // linear LDS byte = chunk*1024 + lane*16 ; row = chunk*8 + (lane>>3)
  // element (row,col) lives at byte row*128 + ((col*2) ^ ((row&7)<<4))
  const int l8   = lane >> 3;                              // row within 8-row chunk
  const int scol = ((((lane & 7) << 4) ^ (l8 << 4)) >> 1); // source col (elements)

  const unsigned short* Ag[4]; const unsigned short* Bg[4];
  unsigned short* Al[4]; unsigned short* Bl[4];
  #pragma unroll
  for (int i = 0; i < 4; ++i){
    const int row = wid*32 + i*8 + l8;
    Ag[i] = A + (size_t)(bm + row) * (size_t)0 + 0; // placeholder, set below
    (void)Ag;
    Al[i] = As + (wid*4 + i) * 512;
    Bl[i] = Bs + (wid*4 + i) * 512;
  }
  // K (leading dim) differs per call; recompute pointers with true stride:
  // A row stride = K_total. We pass KS as the per-block chunk; the true leading
  // dimension is gridDim.z * KS.
  const int Klead = gridDim.z * KS;
  #pragma unroll
  for (int i = 0; i < 4; ++i){
    const int row = wid*32 + i*8 + l8;
    Ag[i] = A + (size_t)(bm + row) * Klead + scol;
    Bg[i] = B + (size_t)(bn + row) * Klead + scol;
  }

  // ---- fragment read geometry ----
  const int fr    = lane & 15;
  const int fk    = (lane >> 4) << 4;      // byte offset of k-group within 32-elem slab
  const int amask = (fr & 7) << 4;         // swizzle mask (row&7)<<4

  for (int k0 = kb; k0 < ke; k0 += 64){
    if (k0 != kb) __syncthreads();
    #pragma unroll
    for (int i = 0; i < 4; ++i){
      gload_lds16(Ag[i] + k0, Al[i]);
      gload_lds16(Bg[i] + k0, Bl[i]);
    }
    __syncthreads();
    #pragma unroll
    for (int kk = 0; kk < 2; ++kk){
      s16x8 af[4], bf[4];
      #pragma unroll
      for (int m = 0; m < 4; ++m){
        const int row = (wr << 6) + m*16 + fr;
        const int off = row*128 + (((kk << 6) + fk) ^ amask);
        af[m] = *(const s16x8*)((const char*)As + off);
      }
      #pragma unroll
      for (int n = 0; n < 4; ++n){
        const int row = (wc << 6) + n*16 + fr;
        const int off = row*128 + (((kk << 6) + fk) ^ amask);
        bf[n] = *(const s16x8*)((const char*)Bs + off);
      }
      #pragma unroll
      for (int m = 0; m < 4; ++m)
        #pragma unroll
        for (int n = 0; n < 4; ++n)
          acc[m][n] = __builtin_amdgcn_mfma_f32_16x16x32_bf16(af[m], bf[n], acc[m][n], 0, 0, 0);
    }
  }

  // ---- epilogue ----
  const int gr0 = bm + (wr << 6) + ((lane >> 4) << 2);
  const int gc0 = bn + (wc << 6) + (lane & 15);
  const size_t pbase = (size_t)blockIdx.z * M * N;
  #pragma unroll
  for (int m = 0; m < 4; ++m){
    #pragma unroll
    for (int n = 0; n < 4; ++n){
      #pragma unroll
      for (int j = 0; j < 4; ++j){
        const int row = gr0 + m*16 + j;
        const int col = gc0 + n*16;
        const size_t idx = (size_t)row * N + col;
        const float v = acc[m][n][j];
        if      (EPI == 0) Cf[idx] = v * scale;
        else if (EPI == 1) Cb[idx] = f2b(v * scale);
        else if (EPI == 2) Cb[idx] = f2b(v + bias[row]);
        else if (EPI == 4) Cf[pbase + idx] = v;
      }
    }
  }
}

// split-K reduce: Cf[i] += sum_s P[s][i]; Cb[i] = bf16(Cf[i]); 4 floats/thread
__global__ __launch_bounds__(256) void reduce_splitk(
    const float* __restrict__ P, int S, size_t stride4,
    float* __restrict__ Cf, unsigned short* __restrict__ Cb, int n4)
{
  const int i = blockIdx.x * 256 + threadIdx.x;
  if (i >= n4) return;
  f32x4 s = ((const f32x4*)Cf)[i];
  for (int k = 0; k < S; ++k) s += ((const f32x4*)P)[(size_t)k * stride4 + i];
  ((f32x4*)Cf)[i] = s;
  u16x4 o;
  o[0] = f2b(s[0]); o[1] = f2b(s[1]); o[2] = f2b(s[2]); o[3] = f2b(s[3]);
  ((u16x4*)Cb)[i] = o;
}

// fp32 -> (optional fp32 copy) + bf16, 8 elements/thread
__global__ void cvt8(const float* __restrict__ src, float* __restrict__ dstf,
                     unsigned short* __restrict__ dstb, int n8)
{
  const int i = blockIdx.x * 256 + threadIdx.x;
  if (i >= n8) return;
  const f32x4 a = ((const f32x4*)src)[2*i];
  const f32x4 b = ((const f32x4*)src)[2*i + 1];
  if (dstf){ ((f32x4*)dstf)[2*i] = a; ((f32x4*)dstf)[2*i + 1] = b; }
  u16x8 o;
  o[0]=f2b(a[0]); o[1]=f2b(a[1]); o[2]=f2b(a[2]); o[3]=f2b(a[3]);
  o[4]=f2b(b[0]); o[5]=f2b(b[1]); o[6]=f2b(b[2]); o[7]=f2b(b[3]);
  ((u16x8*)dstb)[i] = o;
}

// softmax over 4096 fp32 cols, one block (256 thr) per row -> bf16 att
__global__ __launch_bounds__(256) void softmax_f32(const float* __restrict__ z,
                                                   unsigned short* __restrict__ att)
{
  const int row = blockIdx.x, t = threadIdx.x;
  const int lane = t & 63, wid = t >> 6;
  __shared__ float red[4];
  const f32x4* zr = (const f32x4*)(z + (size_t)row * 4096) + t*4;
  f32x4 v[4];
  #pragma unroll
  for (int i = 0; i < 4; ++i) v[i] = zr[i];
  float m = -3.0e38f;
  #pragma unroll
  for (int i = 0; i < 4; ++i)
    #pragma unroll
    for (int j = 0; j < 4; ++j) m = fmaxf(m, v[i][j]);
  #pragma unroll
  for (int o = 32; o; o >>= 1) m = fmaxf(m, __shfl_xor(m, o, 64));
  if (lane == 0) red[wid] = m;
  __syncthreads();
  m = fmaxf(fmaxf(red[0], red[1]), fmaxf(red[2], red[3]));
  float e[16]; float s = 0.f;
  #pragma unroll
  for (int i = 0; i < 4; ++i)
    #pragma unroll
    for (int j = 0; j < 4; ++j){ const float x = __expf(v[i][j] - m); e[i*4+j] = x; s += x; }
  #pragma unroll
  for (int o = 32; o; o >>= 1) s += __shfl_xor(s, o, 64);
  __syncthreads();
  if (lane == 0) red[wid] = s;
  __syncthreads();
  s = red[0] + red[1] + red[2] + red[3];
  const float inv = 1.0f / s;
  u16x8 o0, o1;
  #pragma unroll
  for (int j = 0; j < 8; ++j){ o0[j] = f2b(e[j] * inv); o1[j] = f2b(e[8+j] * inv); }
  u16x8* out = (u16x8*)(att + (size_t)row * 4096 + t*16);
  out[0] = o0; out[1] = o1;
}

// in-place softmax over 16384 bf16 cols, one block (1024 thr) per row
__global__ __launch_bounds__(1024) void softmax_b16(unsigned short* __restrict__ z2)
{
  const int row = blockIdx.x, t = threadIdx.x;
  const int lane = t & 63, wid = t >> 6;
  __shared__ float red[16];
  u16x8* p = (u16x8*)(z2 + (size_t)row * 16384 + t*16);
  const u16x8 a0 = p[0], a1 = p[1];
  float x[16];
  #pragma unroll
  for (int j = 0; j < 8; ++j){ x[j] = b2f(a0[j]); x[8+j] = b2f(a1[j]); }
  float m = -3.0e38f;
  #pragma unroll
  for (int j = 0; j < 16; ++j) m = fmaxf(m, x[j]);
  #pragma unroll
  for (int o = 32; o; o >>= 1) m = fmaxf(m, __shfl_xor(m, o, 64));
  if (lane == 0) red[wid] = m;
  __syncthreads();
  #pragma unroll
  for (int i = 0; i < 16; ++i) m = fmaxf(m, red[i]);
  float e[16]; float s = 0.f;
  #pragma unroll
  for (int j = 0; j < 16; ++j){ const float xx = __expf(x[j] - m); e[j] = xx; s += xx; }
  #pragma unroll
  for (int o = 32; o; o >>= 1) s += __shfl_xor(s, o, 64);
  __syncthreads();
  if (lane == 0) red[wid] = s;
  __syncthreads();
  s = 0.f;
  #pragma unroll
  for (int i = 0; i < 16; ++i) s += red[i];
  const float inv = 1.0f / s;
  u16x8 o0, o1;
  #pragma unroll
  for (int j = 0; j < 8; ++j){ o0[j] = f2b(e[j] * inv); o1[j] = f2b(e[8+j] * inv); }
  p[0] = o0; p[1] = o1;
}

extern "C" void kernel_launch(void* const* d_in, const int* in_sizes, int n_in,
                              void* d_out, int out_size, void* d_ws, size_t ws_size,
                              hipStream_t stream)
{
  (void)in_sizes; (void)n_in; (void)out_size; (void)ws_size;
  const float* sents = (const float*)d_in[0];
  const float* funcs = (const float*)d_in[1];
  const float* WvA   = (const float*)d_in[2];   // Wv_f2s
  const float* bvA   = (const float*)d_in[3];
  const float* WvB   = (const float*)d_in[4];   // Wv_s2f
  const float* bvB   = (const float*)d_in[5];

  const int NS = 16384, NF = 4096, D = 768;

  float* outS = (float*)d_out;                        // [NS, D]
  float* outF = outS + (size_t)NS * D;                // [NF, D]
  float* outZ = outF + (size_t)NF * D;                // [NS, NF]

  char* ws = (char*)d_ws;
  unsigned short* att = (unsigned short*)ws;  ws += (size_t)NS * NF * 2;   // shared att / z2 buffer
  unsigned short* z2  = att;                                               // disjoint lifetimes
  unsigned short* sb  = (unsigned short*)ws;  ws += (size_t)NS * D * 2;
  unsigned short* fb  = (unsigned short*)ws;  ws += (size_t)NF * D * 2;
  unsigned short* fvT = (unsigned short*)ws;  ws += (size_t)D * NF * 2;
  unsigned short* svT = (unsigned short*)ws;  ws += (size_t)D * NS * 2;
  unsigned short* wA  = (unsigned short*)ws;  ws += (size_t)D * D * 2;
  unsigned short* wB  = (unsigned short*)ws;  ws += (size_t)D * D * 2;
  float* Pbuf = (float*)ws;  ws += (size_t)NS * D * 2 * 4;   // 100.7 MB split-K partials
                                                             // (16384*768*2 == 4096*768*8)

  const float scale = 0.036084391824351615f;  // 1/sqrt(768)

  cvt8<<<dim3((NS*D/8 + 255)/256), 256, 0, stream>>>(sents, outS, sb, NS*D/8);
  cvt8<<<dim3((NF*D/8 + 255)/256), 256, 0, stream>>>(funcs, outF, fb, NF*D/8);
  cvt8<<<dim3((D*D/8 + 255)/256),  256, 0, stream>>>(WvA, nullptr, wA, D*D/8);
  cvt8<<<dim3((D*D/8 + 255)/256),  256, 0, stream>>>(WvB, nullptr, wB, D*D/8);

  for (int it = 0; it < 4; ++it){
    // fvT[d][f] = sum_k Wv_f2s[d][k]*func_hid[f][k] + bv_f2s[d]   (= func_val^T)
    gemm_bt<2><<<dim3(NF/128, D/128, 1), dim3(256), 0, stream>>>(wA, fb, D, NF, D, 0.f, bvA, nullptr, fvT);
    // z = scale * sents_hid @ func_hid^T   (fp32, in d_out)
    gemm_bt<0><<<dim3(NF/128, NS/128, 1), dim3(256), 0, stream>>>(sb, fb, NS, NF, D, scale, nullptr, outZ, nullptr);
    softmax_f32<<<NS, 256, 0, stream>>>(outZ, att);
    // sents_hid += att @ func_val : split-K S=2 (K=4096 -> 2048/chunk), then reduce
    gemm_bt<4><<<dim3(D/128, NS/128, 2), dim3(256), 0, stream>>>(att, fvT, NS, D, 2048, 0.f, nullptr, Pbuf, nullptr);
    reduce_splitk<<<dim3(NS*D/4/256), 256, 0, stream>>>(Pbuf, 2, (size_t)NS*D/4, outS, sb, NS*D/4);
    // svT[d][s] = sum_k Wv_s2f[d][k]*sents_hid[s][k] + bv_s2f[d]  (= sent_val^T)
    gemm_bt<2><<<dim3(NS/128, D/128, 1), dim3(256), 0, stream>>>(wB, sb, D, NS, D, 0.f, bvB, nullptr, svT);
    // z2 = scale * func_hid @ sents_hid^T   (bf16)
    gemm_bt<1><<<dim3(NS/128, NF/128, 1), dim3(256), 0, stream>>>(fb, sb, NF, NS, D, scale, nullptr, nullptr, z2);
    softmax_b16<<<NF, 1024, 0, stream>>>(z2);
    // func_hid += att2 @ sent_val : split-K S=8 (K=16384 -> 2048/chunk), then reduce
    gemm_bt<4><<<dim3(D/128, NF/128, 8), dim3(256), 0, stream>>>(z2, svT, NF, D, 2048, 0.f, nullptr, Pbuf, nullptr);
    reduce_splitk<<<dim3(NF*D/4/256), 256, 0, stream>>>(Pbuf, 8, (size_t)NF*D/4, outF, fb, NF*D/4);
  }
}

// Round 3
// 2776.356 us; speedup vs baseline: 1.2163x; 1.1442x over previous
//
#include <hip/hip_runtime.h>
#include <stdint.h>

typedef __attribute__((ext_vector_type(8))) short s16x8;
typedef __attribute__((ext_vector_type(8))) unsigned short u16x8;
typedef __attribute__((ext_vector_type(4))) unsigned short u16x4;
typedef __attribute__((ext_vector_type(4))) float f32x4;

__device__ inline unsigned short f2b(float f){
  unsigned u = __builtin_bit_cast(unsigned, f);
  u = u + 0x7fffu + ((u >> 16) & 1u);
  return (unsigned short)(u >> 16);
}
__device__ inline float b2f(unsigned short h){
  unsigned u = ((unsigned)h) << 16;
  return __builtin_bit_cast(float, u);
}

typedef __attribute__((address_space(1))) const unsigned g_uint;
typedef __attribute__((address_space(3))) unsigned l_uint;

__device__ inline void gload_lds16(const void* g, void* l){
  __builtin_amdgcn_global_load_lds((g_uint*)reinterpret_cast<uintptr_t>(g),
                                   (l_uint*)reinterpret_cast<uintptr_t>(l), 16, 0, 0);
}

// C[m][n] = sum_k A[m][k] * B[n][k]   (A: [M,K], B: [N,K], both row-major bf16)
// K range per block: [bz*KS, bz*KS+KS);  leading dim = gridDim.z * KS
// EPI 0: Cf[idx] = v*scale                       (fp32 out)
// EPI 1: Cb[idx] = bf16(v*scale)
// EPI 2: Cb[idx] = bf16(v + bias[row])
// EPI 4: Cf[bz*M*N + idx] = v                    (split-K partial)
template<int EPI>
__global__ __launch_bounds__(256, 2) void gemm_bt(
    const unsigned short* __restrict__ A, const unsigned short* __restrict__ B,
    int M, int N, int KS, float scale, const float* __restrict__ bias,
    float* __restrict__ Cf, unsigned short* __restrict__ Cb)
{
  __shared__ unsigned short As[128*64];
  __shared__ unsigned short Bs[128*64];
  const int tid  = threadIdx.x;
  const int wid  = tid >> 6, lane = tid & 63;
  const int wr   = wid >> 1, wc = wid & 1;

  // ---- bijective XCD-aware swizzle (all launch grids have total % 8 == 0) ----
  // Consecutive work-ids share the A row-panel; keep them on one XCD's L2.
  const unsigned gx = gridDim.x, gy = gridDim.y;
  const unsigned lin = blockIdx.x + gx*(blockIdx.y + gy*blockIdx.z);
  const unsigned q   = (gx*gy*gridDim.z) >> 3;
  const unsigned w   = (lin & 7)*q + (lin >> 3);
  const unsigned bxs = w % gx;
  const unsigned rest = w / gx;
  const unsigned bys = rest % gy;
  const unsigned bzs = rest / gy;

  const int bm   = bys * 128, bn = bxs * 128;
  const int kb   = bzs * KS, ke = kb + KS;

  f32x4 acc[4][4] = {};

  // ---- staging geometry (global source pre-swizzled; LDS written linearly) ----
  // linear LDS byte = chunk*1024 + lane*16 ; row = chunk*8 + (lane>>3)
  // element (row,col) lives at byte row*128 + ((col*2) ^ ((row&7)<<4))
  const int l8   = lane >> 3;                              // row within 8-row chunk
  const int scol = ((((lane & 7) << 4) ^ (l8 << 4)) >> 1); // source col (elements)
  const int Klead = gridDim.z * KS;

  const unsigned short* Ag[4]; const unsigned short* Bg[4];
  unsigned short* Al[4]; unsigned short* Bl[4];
  #pragma unroll
  for (int i = 0; i < 4; ++i){
    const int row = wid*32 + i*8 + l8;
    Ag[i] = A + (size_t)(bm + row) * Klead + scol;
    Bg[i] = B + (size_t)(bn + row) * Klead + scol;
    Al[i] = As + (wid*4 + i) * 512;
    Bl[i] = Bs + (wid*4 + i) * 512;
  }

  // ---- fragment read geometry ----
  const int fr    = lane & 15;
  const int fk    = (lane >> 4) << 4;      // byte offset of k-group within 32-elem slab
  const int amask = (fr & 7) << 4;         // swizzle mask (row&7)<<4

  for (int k0 = kb; k0 < ke; k0 += 64){
    if (k0 != kb) __syncthreads();
    #pragma unroll
    for (int i = 0; i < 4; ++i){
      gload_lds16(Ag[i] + k0, Al[i]);
      gload_lds16(Bg[i] + k0, Bl[i]);
    }
    __syncthreads();
    #pragma unroll
    for (int kk = 0; kk < 2; ++kk){
      s16x8 af[4], bf[4];
      #pragma unroll
      for (int m = 0; m < 4; ++m){
        const int row = (wr << 6) + m*16 + fr;
        const int off = row*128 + (((kk << 6) + fk) ^ amask);
        af[m] = *(const s16x8*)((const char*)As + off);
      }
      #pragma unroll
      for (int n = 0; n < 4; ++n){
        const int row = (wc << 6) + n*16 + fr;
        const int off = row*128 + (((kk << 6) + fk) ^ amask);
        bf[n] = *(const s16x8*)((const char*)Bs + off);
      }
      #pragma unroll
      for (int m = 0; m < 4; ++m)
        #pragma unroll
        for (int n = 0; n < 4; ++n)
          acc[m][n] = __builtin_amdgcn_mfma_f32_16x16x32_bf16(af[m], bf[n], acc[m][n], 0, 0, 0);
    }
  }

  // ---- epilogue ----
  const int gr0 = bm + (wr << 6) + ((lane >> 4) << 2);
  const int gc0 = bn + (wc << 6) + (lane & 15);
  const size_t pbase = (size_t)bzs * M * N;
  #pragma unroll
  for (int m = 0; m < 4; ++m){
    #pragma unroll
    for (int n = 0; n < 4; ++n){
      #pragma unroll
      for (int j = 0; j < 4; ++j){
        const int row = gr0 + m*16 + j;
        const int col = gc0 + n*16;
        const size_t idx = (size_t)row * N + col;
        const float v = acc[m][n][j];
        if      (EPI == 0) Cf[idx] = v * scale;
        else if (EPI == 1) Cb[idx] = f2b(v * scale);
        else if (EPI == 2) Cb[idx] = f2b(v + bias[row]);
        else if (EPI == 4) Cf[pbase + idx] = v;
      }
    }
  }
}

// split-K reduce: Cf[i] += sum_s P[s][i]; Cb[i] = bf16(Cf[i]); 4 floats/thread
__global__ __launch_bounds__(256) void reduce_splitk(
    const float* __restrict__ P, int S, size_t stride4,
    float* __restrict__ Cf, unsigned short* __restrict__ Cb, int n4)
{
  const int i = blockIdx.x * 256 + threadIdx.x;
  if (i >= n4) return;
  f32x4 s = ((const f32x4*)Cf)[i];
  for (int k = 0; k < S; ++k) s += ((const f32x4*)P)[(size_t)k * stride4 + i];
  ((f32x4*)Cf)[i] = s;
  u16x4 o;
  o[0] = f2b(s[0]); o[1] = f2b(s[1]); o[2] = f2b(s[2]); o[3] = f2b(s[3]);
  ((u16x4*)Cb)[i] = o;
}

// fp32 -> (optional fp32 copy) + bf16, 8 elements/thread
__global__ void cvt8(const float* __restrict__ src, float* __restrict__ dstf,
                     unsigned short* __restrict__ dstb, int n8)
{
  const int i = blockIdx.x * 256 + threadIdx.x;
  if (i >= n8) return;
  const f32x4 a = ((const f32x4*)src)[2*i];
  const f32x4 b = ((const f32x4*)src)[2*i + 1];
  if (dstf){ ((f32x4*)dstf)[2*i] = a; ((f32x4*)dstf)[2*i + 1] = b; }
  u16x8 o;
  o[0]=f2b(a[0]); o[1]=f2b(a[1]); o[2]=f2b(a[2]); o[3]=f2b(a[3]);
  o[4]=f2b(b[0]); o[5]=f2b(b[1]); o[6]=f2b(b[2]); o[7]=f2b(b[3]);
  ((u16x8*)dstb)[i] = o;
}

// softmax over 4096 fp32 cols, one block (256 thr) per row -> bf16 att
__global__ __launch_bounds__(256) void softmax_f32(const float* __restrict__ z,
                                                   unsigned short* __restrict__ att)
{
  const int row = blockIdx.x, t = threadIdx.x;
  const int lane = t & 63, wid = t >> 6;
  __shared__ float red[4];
  const f32x4* zr = (const f32x4*)(z + (size_t)row * 4096) + t*4;
  f32x4 v[4];
  #pragma unroll
  for (int i = 0; i < 4; ++i) v[i] = zr[i];
  float m = -3.0e38f;
  #pragma unroll
  for (int i = 0; i < 4; ++i)
    #pragma unroll
    for (int j = 0; j < 4; ++j) m = fmaxf(m, v[i][j]);
  #pragma unroll
  for (int o = 32; o; o >>= 1) m = fmaxf(m, __shfl_xor(m, o, 64));
  if (lane == 0) red[wid] = m;
  __syncthreads();
  m = fmaxf(fmaxf(red[0], red[1]), fmaxf(red[2], red[3]));
  float e[16]; float s = 0.f;
  #pragma unroll
  for (int i = 0; i < 4; ++i)
    #pragma unroll
    for (int j = 0; j < 4; ++j){ const float x = __expf(v[i][j] - m); e[i*4+j] = x; s += x; }
  #pragma unroll
  for (int o = 32; o; o >>= 1) s += __shfl_xor(s, o, 64);
  __syncthreads();
  if (lane == 0) red[wid] = s;
  __syncthreads();
  s = red[0] + red[1] + red[2] + red[3];
  const float inv = 1.0f / s;
  u16x8 o0, o1;
  #pragma unroll
  for (int j = 0; j < 8; ++j){ o0[j] = f2b(e[j] * inv); o1[j] = f2b(e[8+j] * inv); }
  u16x8* out = (u16x8*)(att + (size_t)row * 4096 + t*16);
  out[0] = o0; out[1] = o1;
}

// in-place softmax over 4096 bf16 cols, one block (256 thr) per row
__global__ __launch_bounds__(256) void softmax_b16_4k(unsigned short* __restrict__ z)
{
  const int row = blockIdx.x, t = threadIdx.x;
  const int lane = t & 63, wid = t >> 6;
  __shared__ float red[4];
  u16x8* p = (u16x8*)(z + (size_t)row * 4096 + t*16);
  const u16x8 a0 = p[0], a1 = p[1];
  float x[16];
  #pragma unroll
  for (int j = 0; j < 8; ++j){ x[j] = b2f(a0[j]); x[8+j] = b2f(a1[j]); }
  float m = -3.0e38f;
  #pragma unroll
  for (int j = 0; j < 16; ++j) m = fmaxf(m, x[j]);
  #pragma unroll
  for (int o = 32; o; o >>= 1) m = fmaxf(m, __shfl_xor(m, o, 64));
  if (lane == 0) red[wid] = m;
  __syncthreads();
  m = fmaxf(fmaxf(red[0], red[1]), fmaxf(red[2], red[3]));
  float e[16]; float s = 0.f;
  #pragma unroll
  for (int j = 0; j < 16; ++j){ const float xx = __expf(x[j] - m); e[j] = xx; s += xx; }
  #pragma unroll
  for (int o = 32; o; o >>= 1) s += __shfl_xor(s, o, 64);
  __syncthreads();
  if (lane == 0) red[wid] = s;
  __syncthreads();
  s = red[0] + red[1] + red[2] + red[3];
  const float inv = 1.0f / s;
  u16x8 o0, o1;
  #pragma unroll
  for (int j = 0; j < 8; ++j){ o0[j] = f2b(e[j] * inv); o1[j] = f2b(e[8+j] * inv); }
  p[0] = o0; p[1] = o1;
}

// in-place softmax over 16384 bf16 cols, one block (1024 thr) per row
__global__ __launch_bounds__(1024) void softmax_b16(unsigned short* __restrict__ z2)
{
  const int row = blockIdx.x, t = threadIdx.x;
  const int lane = t & 63, wid = t >> 6;
  __shared__ float red[16];
  u16x8* p = (u16x8*)(z2 + (size_t)row * 16384 + t*16);
  const u16x8 a0 = p[0], a1 = p[1];
  float x[16];
  #pragma unroll
  for (int j = 0; j < 8; ++j){ x[j] = b2f(a0[j]); x[8+j] = b2f(a1[j]); }
  float m = -3.0e38f;
  #pragma unroll
  for (int j = 0; j < 16; ++j) m = fmaxf(m, x[j]);
  #pragma unroll
  for (int o = 32; o; o >>= 1) m = fmaxf(m, __shfl_xor(m, o, 64));
  if (lane == 0) red[wid] = m;
  __syncthreads();
  #pragma unroll
  for (int i = 0; i < 16; ++i) m = fmaxf(m, red[i]);
  float e[16]; float s = 0.f;
  #pragma unroll
  for (int j = 0; j < 16; ++j){ const float xx = __expf(x[j] - m); e[j] = xx; s += xx; }
  #pragma unroll
  for (int o = 32; o; o >>= 1) s += __shfl_xor(s, o, 64);
  __syncthreads();
  if (lane == 0) red[wid] = s;
  __syncthreads();
  s = 0.f;
  #pragma unroll
  for (int i = 0; i < 16; ++i) s += red[i];
  const float inv = 1.0f / s;
  u16x8 o0, o1;
  #pragma unroll
  for (int j = 0; j < 8; ++j){ o0[j] = f2b(e[j] * inv); o1[j] = f2b(e[8+j] * inv); }
  p[0] = o0; p[1] = o1;
}

extern "C" void kernel_launch(void* const* d_in, const int* in_sizes, int n_in,
                              void* d_out, int out_size, void* d_ws, size_t ws_size,
                              hipStream_t stream)
{
  (void)in_sizes; (void)n_in; (void)out_size; (void)ws_size;
  const float* sents = (const float*)d_in[0];
  const float* funcs = (const float*)d_in[1];
  const float* WvA   = (const float*)d_in[2];   // Wv_f2s
  const float* bvA   = (const float*)d_in[3];
  const float* WvB   = (const float*)d_in[4];   // Wv_s2f
  const float* bvB   = (const float*)d_in[5];

  const int NS = 16384, NF = 4096, D = 768;

  float* outS = (float*)d_out;                        // [NS, D]
  float* outF = outS + (size_t)NS * D;                // [NF, D]
  float* outZ = outF + (size_t)NF * D;                // [NS, NF]

  char* ws = (char*)d_ws;
  unsigned short* att = (unsigned short*)ws;  ws += (size_t)NS * NF * 2;   // shared att / z2 buffer
  unsigned short* z2  = att;                                               // disjoint lifetimes
  unsigned short* sb  = (unsigned short*)ws;  ws += (size_t)NS * D * 2;
  unsigned short* fb  = (unsigned short*)ws;  ws += (size_t)NF * D * 2;
  unsigned short* fvT = (unsigned short*)ws;  ws += (size_t)D * NF * 2;
  unsigned short* svT = (unsigned short*)ws;  ws += (size_t)D * NS * 2;
  unsigned short* wA  = (unsigned short*)ws;  ws += (size_t)D * D * 2;
  unsigned short* wB  = (unsigned short*)ws;  ws += (size_t)D * D * 2;
  float* Pbuf = (float*)ws;  ws += (size_t)NS * D * 2 * 4;   // 100.7 MB split-K partials
                                                             // (16384*768*2 == 4096*768*8)

  const float scale = 0.036084391824351615f;  // 1/sqrt(768)

  cvt8<<<dim3((NS*D/8 + 255)/256), 256, 0, stream>>>(sents, outS, sb, NS*D/8);
  cvt8<<<dim3((NF*D/8 + 255)/256), 256, 0, stream>>>(funcs, outF, fb, NF*D/8);
  cvt8<<<dim3((D*D/8 + 255)/256),  256, 0, stream>>>(WvA, nullptr, wA, D*D/8);
  cvt8<<<dim3((D*D/8 + 255)/256),  256, 0, stream>>>(WvB, nullptr, wB, D*D/8);

  for (int it = 0; it < 4; ++it){
    // fvT[d][f] = sum_k Wv_f2s[d][k]*func_hid[f][k] + bv_f2s[d]   (= func_val^T)
    gemm_bt<2><<<dim3(NF/128, D/128, 1), dim3(256), 0, stream>>>(wA, fb, D, NF, D, 0.f, bvA, nullptr, fvT);
    if (it < 3){
      // z only needed for softmax -> bf16 logits in att, softmax in place
      gemm_bt<1><<<dim3(NF/128, NS/128, 1), dim3(256), 0, stream>>>(sb, fb, NS, NF, D, scale, nullptr, nullptr, att);
      softmax_b16_4k<<<NS, 256, 0, stream>>>(att);
    } else {
      // z = scale * sents_hid @ func_hid^T   (fp32, returned in d_out)
      gemm_bt<0><<<dim3(NF/128, NS/128, 1), dim3(256), 0, stream>>>(sb, fb, NS, NF, D, scale, nullptr, outZ, nullptr);
      softmax_f32<<<NS, 256, 0, stream>>>(outZ, att);
    }
    // sents_hid += att @ func_val : split-K S=2 (K=4096 -> 2048/chunk), then reduce
    gemm_bt<4><<<dim3(D/128, NS/128, 2), dim3(256), 0, stream>>>(att, fvT, NS, D, 2048, 0.f, nullptr, Pbuf, nullptr);
    reduce_splitk<<<dim3(NS*D/4/256), 256, 0, stream>>>(Pbuf, 2, (size_t)NS*D/4, outS, sb, NS*D/4);
    // svT[d][s] = sum_k Wv_s2f[d][k]*sents_hid[s][k] + bv_s2f[d]  (= sent_val^T)
    gemm_bt<2><<<dim3(NS/128, D/128, 1), dim3(256), 0, stream>>>(wB, sb, D, NS, D, 0.f, bvB, nullptr, svT);
    // z2 = scale * func_hid @ sents_hid^T   (bf16)
    gemm_bt<1><<<dim3(NS/128, NF/128, 1), dim3(256), 0, stream>>>(fb, sb, NF, NS, D, scale, nullptr, nullptr, z2);
    softmax_b16<<<NF, 1024, 0, stream>>>(z2);
    // func_hid += att2 @ sent_val : split-K S=8 (K=16384 -> 2048/chunk), then reduce
    gemm_bt<4><<<dim3(D/128, NF/128, 8), dim3(256), 0, stream>>>(z2, svT, NF, D, 2048, 0.f, nullptr, Pbuf, nullptr);
    reduce_splitk<<<dim3(NF*D/4/256), 256, 0, stream>>>(Pbuf, 8, (size_t)NF*D/4, outF, fb, NF*D/4);
  }
}